// Round 26
// baseline (353.120 us; speedup 1.0000x reference)
//
#include <hip/hip_runtime.h>
#include <climits>

// R26: staging retained (R25's direct writes caused 508MB uncoalesced WRITE),
// but (a) all-lane piecewise copy-out via staged flu, (b) 2048-pt chunks
// halve LDS -> 5 blocks/CU (62% occ vs R24's 30%).
static constexpr int kN = 8388608;
static constexpr int kNumCells = 3216822;     // fallback cell array
static constexpr int kMaxFlat = 2560800;      // 3*640000 + 800*800 + 800
static constexpr int kNBk = (kMaxFlat >> 12) + 1;   // 626 buckets x 4096 cells
static constexpr int kCap = 16384;            // per-bucket capacity (~22% slack)
static constexpr int kChunk = 2048;           // points per part-block

typedef float __attribute__((ext_vector_type(4))) f32x4;
typedef int   __attribute__((ext_vector_type(4))) i32x4;

__device__ __align__(16) unsigned long long g_keyb[(unsigned)kNBk * kCap]; // hbits<<32|idx
__device__ __align__(16) unsigned short g_cellb[(unsigned)kNBk * kCap];    // flat & 4095
__device__ unsigned g_cursor[kNBk * 16];      // 64B-padded cursors
__device__ unsigned long long g_cell[kNumCells];   // fallback path only
__device__ int g_minr = INT_MAX, g_maxr = INT_MIN;
__device__ int g_minc = INT_MAX, g_maxc = INT_MIN;
__device__ int g_fb = 0;

__device__ __forceinline__ int quant(float v) {
    return (int)rintf(v * 40.0f);   // np-ref rule (proven R11/R12)
}
__device__ __forceinline__ bool okfast() {
    return g_minr == 0 && g_maxr == 800 && g_minc == 0 && g_maxc == 800;
}

__global__ void k_cursor() {
    int i = blockIdx.x * blockDim.x + threadIdx.x;
    if (i < kNBk) g_cursor[i << 4] = (unsigned)(i * kCap);
}

// Fused: blocks [0,zb) zero out[]; blocks [zb,..) partition 2048-pt chunks.
__global__ void __launch_bounds__(256) k_main(const float* __restrict__ xyz,
                                              const int* __restrict__ bidx, int n,
                                              float* __restrict__ out, int total,
                                              int zb) {
    const int tid = threadIdx.x;
    if (blockIdx.x < zb) {
        int t = blockIdx.x * blockDim.x + tid;
        int S = zb * blockDim.x;
        float4 f4 = make_float4(0.f, 0.f, 0.f, 0.f);
        float4* o4 = (float4*)out;
        const int no4 = total >> 2;
        for (int i = t; i < no4; i += S) o4[i] = f4;
        for (int i = (no4 << 2) + t; i < total; i += S) out[i] = 0.f;
        return;
    }
    const int chunk0 = (blockIdx.x - zb) * kChunk;
    if (chunk0 >= n) return;

    __shared__ unsigned s_cnt[kNBk], s_scan[kNBk], s_gbase[kNBk];
    __shared__ unsigned s_wsum[4];
    __shared__ int s_mm[4][4];
    __shared__ unsigned long long s_key[kChunk];
    __shared__ unsigned s_flu[kChunk];
    for (int i = tid; i < kNBk; i += 256) s_cnt[i] = 0;
    __syncthreads();

    // --- 8 points/thread, constant-indexed state (VGPR-resident) ---
    unsigned hb[8], flu[8], rank[8];
    bool val[8];
    int mnr = INT_MAX, mxr = INT_MIN, mnc = INT_MAX, mxc = INT_MIN;
    const f32x4* p = (const f32x4*)xyz;
    const i32x4* bp = (const i32x4*)bidx;
    const int g0 = (chunk0 >> 2) + tid;     // 4-pt group id, +256 per round
#pragma unroll
    for (int k = 0; k < 2; ++k) {
        const int gidx = g0 + (k << 8);
        const int pbase = gidx << 2;
        float xs[4], hs[4], zs[4]; int bs[4];
        if (pbase + 3 < n) {
            f32x4 f0 = p[3 * gidx + 0];   // x0 h0 z0 x1
            f32x4 f1 = p[3 * gidx + 1];   // h1 z1 x2 h2
            f32x4 f2 = p[3 * gidx + 2];   // z2 x3 h3 z3
            i32x4 b4 = bp[gidx];
            xs[0]=f0.x; hs[0]=f0.y; zs[0]=f0.z;
            xs[1]=f0.w; hs[1]=f1.x; zs[1]=f1.y;
            xs[2]=f1.z; hs[2]=f1.w; zs[2]=f2.x;
            xs[3]=f2.y; hs[3]=f2.z; zs[3]=f2.w;
            bs[0]=b4.x; bs[1]=b4.y; bs[2]=b4.z; bs[3]=b4.w;
        } else {
#pragma unroll
            for (int j = 0; j < 4; ++j) {
                int i = pbase + j;
                bool v = i < n;
                xs[j] = v ? xyz[3 * i + 0] : 0.f;
                hs[j] = v ? xyz[3 * i + 1] : 0.f;
                zs[j] = v ? xyz[3 * i + 2] : 0.f;
                bs[j] = v ? bidx[i] : 0;
            }
        }
#pragma unroll
        for (int j = 0; j < 4; ++j) {
            const int e = (k << 2) + j;           // constant index
            bool v = (pbase + j) < n;
            val[e] = v;
            int qr = quant(zs[j]);
            int qc = quant(xs[j]);
            if (v) {
                mnr = min(mnr, qr); mxr = max(mxr, qr);
                mnc = min(mnc, qc); mxc = max(mxc, qc);
            }
            long long fl = (long long)bs[j] * 640000 + (long long)qr * 800 + qc;
            unsigned f = (unsigned)min(max(fl, 0LL), (long long)kMaxFlat);
            flu[e] = f;
            hb[e] = __float_as_uint(hs[j]);
            rank[e] = v ? (unsigned)atomicAdd(&s_cnt[f >> 12], 1u) : 0u;
        }
    }
    // minmax block-reduce (okfast gate + fallback geometry)
#pragma unroll
    for (int off = 32; off > 0; off >>= 1) {
        mnr = min(mnr, __shfl_down(mnr, off));
        mxr = max(mxr, __shfl_down(mxr, off));
        mnc = min(mnc, __shfl_down(mnc, off));
        mxc = max(mxc, __shfl_down(mxc, off));
    }
    const int w = tid >> 6, lane = tid & 63;
    if (lane == 0) {
        s_mm[w][0] = mnr; s_mm[w][1] = mxr; s_mm[w][2] = mnc; s_mm[w][3] = mxc;
    }
    __syncthreads();   // counts final + minmax partials
    if (tid == 0) {
        atomicMin(&g_minr, min(min(s_mm[0][0], s_mm[1][0]), min(s_mm[2][0], s_mm[3][0])));
        atomicMax(&g_maxr, max(max(s_mm[0][1], s_mm[1][1]), max(s_mm[2][1], s_mm[3][1])));
        atomicMin(&g_minc, min(min(s_mm[0][2], s_mm[1][2]), min(s_mm[2][2], s_mm[3][2])));
        atomicMax(&g_maxc, max(max(s_mm[0][3], s_mm[1][3]), max(s_mm[2][3], s_mm[3][3])));
    }
    // parallel exclusive scan of s_cnt[0..626) -> s_scan
    int e0 = tid * 3;
    unsigned l0 = (e0 + 0 < kNBk) ? s_cnt[e0 + 0] : 0u;
    unsigned l1 = (e0 + 1 < kNBk) ? s_cnt[e0 + 1] : 0u;
    unsigned l2 = (e0 + 2 < kNBk) ? s_cnt[e0 + 2] : 0u;
    unsigned tsum = l0 + l1 + l2;
    unsigned inc = tsum;
#pragma unroll
    for (int off = 1; off < 64; off <<= 1) {
        unsigned v = __shfl_up(inc, off);
        if (lane >= off) inc += v;
    }
    if (lane == 63) s_wsum[w] = inc;
    __syncthreads();
    if (tid == 0) {
        unsigned a = 0;
#pragma unroll
        for (int i = 0; i < 4; ++i) { unsigned t = s_wsum[i]; s_wsum[i] = a; a += t; }
    }
    __syncthreads();
    unsigned excl = inc - tsum + s_wsum[w];
    if (e0 + 0 < kNBk) s_scan[e0 + 0] = excl;
    if (e0 + 1 < kNBk) s_scan[e0 + 1] = excl + l0;
    if (e0 + 2 < kNBk) s_scan[e0 + 2] = excl + l0 + l1;
    __syncthreads();
    // cursor reservation (one padded-line atomic per nonempty bucket)
    for (int i = tid; i < kNBk; i += 256) {
        unsigned c = s_cnt[i];
        if (c) {
            unsigned pos = atomicAdd(&g_cursor[i << 4], c);
            if (pos + c > (unsigned)((i + 1) * kCap)) { g_fb = 1; s_gbase[i] = 0xFFFFFFFFu; }
            else s_gbase[i] = pos;
        }
    }
    // stage bucket-sorted into LDS
#pragma unroll
    for (int e = 0; e < 8; ++e) {
        if (val[e]) {
            const int k = e >> 2, j = e & 3;
            unsigned idx = (unsigned)(((g0 + (k << 8)) << 2) + j);
            unsigned pos = s_scan[flu[e] >> 12] + rank[e];
            s_key[pos] = ((unsigned long long)hb[e] << 32) | idx;
            s_flu[pos] = flu[e];
        }
    }
    __syncthreads();
    // all-lane piecewise-sequential copy-out
    const int nstaged = min(n - chunk0, kChunk);
    for (int i = tid; i < nstaged; i += 256) {
        unsigned f = s_flu[i];
        unsigned bkt = f >> 12;
        unsigned gb = s_gbase[bkt];
        if (gb == 0xFFFFFFFFu) continue;      // overflow -> fallback path
        unsigned dst = gb + ((unsigned)i - s_scan[bkt]);
        g_keyb[dst] = s_key[i];
        g_cellb[dst] = (unsigned short)(f & 4095u);
    }
}

__global__ void k_gate() {
    if (threadIdx.x == 0 && blockIdx.x == 0) {
        if (!okfast()) g_fb = 1;
    }
}

// Per-bucket LDS reduce: max hbits per cell, then min idx among bit-equal
// maxers (== ref's two-scatter). Winners straight to out (pre-zeroed).
__global__ void __launch_bounds__(256) k_reduce(int n, float* __restrict__ out) {
    if (g_fb) return;
    __shared__ unsigned s_hmax[4096], s_imin[4096];
    const int tid = threadIdx.x;
    const int bk = blockIdx.x;
    for (int i = tid; i < 4096; i += 256) { s_hmax[i] = 0u; s_imin[i] = 0xFFFFFFFFu; }
    __syncthreads();
    const unsigned lo = (unsigned)(bk * kCap);
    unsigned hi = g_cursor[bk << 4];
    const unsigned cap = (unsigned)((bk + 1) * kCap);
    if (hi > cap) hi = cap;
    for (unsigned i = lo + tid; i < hi; i += 256)
        atomicMax(&s_hmax[g_cellb[i]], (unsigned)(g_keyb[i] >> 32));
    __syncthreads();
    for (unsigned i = lo + tid; i < hi; i += 256) {
        unsigned long long k = g_keyb[i];
        unsigned c = g_cellb[i];
        if ((unsigned)(k >> 32) == s_hmax[c])
            atomicMin(&s_imin[c], (unsigned)k);
    }
    __syncthreads();
    for (int c = tid; c < 4096; c += 256) {
        unsigned im = s_imin[c];
        if (im != 0xFFFFFFFFu) {
            out[im] = __uint_as_float(s_hmax[c]);   // [0,n) kept_heights
            out[n + im] = 1.0f;                     // [n,2n) keep
        }
    }
}

// ---- gated fallback chain (exact R14 logic; runs only if g_fb) ----
__global__ void k_fb_zero() {
    if (!g_fb) return;
    int i = blockIdx.x * blockDim.x + threadIdx.x;
    int stride = gridDim.x * blockDim.x;
    for (int c = i; c < kNumCells; c += stride) g_cell[c] = 0ULL;
}
__global__ void k_fb_scatter(const float* __restrict__ xyz,
                             const int* __restrict__ bidx, int n) {
    if (!g_fb) return;
    const int minr = g_minr, minc = g_minc;
    const int rmax = g_maxr - minr, cmax = g_maxc - minc;
    int t = blockIdx.x * blockDim.x + threadIdx.x;
    int S = gridDim.x * blockDim.x;
    for (int i = t; i < n; i += S) {
        float x = xyz[3 * i + 0], h = xyz[3 * i + 1], z = xyz[3 * i + 2];
        int qr = quant(z) - minr, qc = quant(x) - minc;
        int flat = bidx[i] * (rmax * cmax) + qr * cmax + qc;
        if (flat >= 0 && flat < kNumCells) {
            unsigned long long key =
                ((unsigned long long)__float_as_uint(h) << 32) | (unsigned)(~i);
            if (key > g_cell[flat]) atomicMax(&g_cell[flat], key);
        }
    }
}
__global__ void k_fb_fin(int n, float* __restrict__ out) {
    if (!g_fb) return;
    int i = blockIdx.x * blockDim.x + threadIdx.x;
    int stride = gridDim.x * blockDim.x;
    for (int c = i; c < kNumCells; c += stride) {
        unsigned long long key = g_cell[c];
        if (key == 0ULL) continue;
        unsigned winner = ~(unsigned)key;
        out[winner] = __uint_as_float((unsigned)(key >> 32));
        out[n + winner] = 1.0f;
    }
}
__global__ void k_reset() {
    if (threadIdx.x == 0 && blockIdx.x == 0) {
        g_fb = 0;
        g_minr = INT_MAX; g_maxr = INT_MIN;
        g_minc = INT_MAX; g_maxc = INT_MIN;
    }
}

extern "C" void kernel_launch(void* const* d_in, const int* in_sizes, int n_in,
                              void* d_out, int out_size, void* d_ws, size_t ws_size,
                              hipStream_t stream) {
    const float* xyz = (const float*)d_in[0];
    const int* bidx = (const int*)d_in[1];
    // d_in[2] (semantics) unused by the reference.
    int n = in_sizes[1];

    const int B = 256;
    const int zb = 512;
    int gridMain = zb + (n + kChunk - 1) / kChunk;  // 512 + 4096
    k_cursor<<<(kNBk + B - 1) / B, B, 0, stream>>>();
    k_main<<<gridMain, B, 0, stream>>>(xyz, bidx, n, (float*)d_out, out_size, zb);
    k_gate<<<1, 64, 0, stream>>>();
    k_reduce<<<kNBk, B, 0, stream>>>(n, (float*)d_out);
    k_fb_zero<<<2048, B, 0, stream>>>();
    k_fb_scatter<<<4096, B, 0, stream>>>(xyz, bidx, n);
    k_fb_fin<<<2048, B, 0, stream>>>(n, (float*)d_out);
    k_reset<<<1, 64, 0, stream>>>();
}

// Round 27
// 267.627 us; speedup vs baseline: 1.3194x; 1.3194x over previous
//
#include <hip/hip_runtime.h>
#include <climits>

// R27: R24's staged partition (4096-pt chunk, run-walk copy-out = best write
// pattern, 214MB) but with 512-thread blocks: same LDS/block => still 3
// blocks/CU but 24 waves/CU (75% theo occ vs R24's 37%). k_gate folded into
// k_reduce's okfast check.
static constexpr int kN = 8388608;
static constexpr int kNumCells = 3216822;     // fallback cell array
static constexpr int kMaxFlat = 2560800;      // 3*640000 + 800*800 + 800
static constexpr int kNBk = (kMaxFlat >> 12) + 1;   // 626 buckets x 4096 cells
static constexpr int kCap = 16384;            // per-bucket cap (mean 13.4K, 26 sigma)
static constexpr int kChunk = 4096;           // points per part-block
static constexpr int kB = 512;                // threads per block (8 waves)

typedef float __attribute__((ext_vector_type(4))) f32x4;
typedef int   __attribute__((ext_vector_type(4))) i32x4;

__device__ __align__(16) unsigned long long g_keyb[(unsigned)kNBk * kCap]; // hbits<<32|idx
__device__ __align__(16) unsigned short g_cellb[(unsigned)kNBk * kCap];    // flat & 4095
__device__ unsigned g_cursor[kNBk * 16];      // 64B-padded cursors
__device__ unsigned long long g_cell[kNumCells];   // fallback path only
__device__ int g_minr = INT_MAX, g_maxr = INT_MIN;
__device__ int g_minc = INT_MAX, g_maxc = INT_MIN;
__device__ int g_fb = 0;

__device__ __forceinline__ int quant(float v) {
    return (int)rintf(v * 40.0f);   // np-ref rule (proven R11/R12)
}
__device__ __forceinline__ bool okfast() {
    return g_minr == 0 && g_maxr == 800 && g_minc == 0 && g_maxc == 800;
}

__global__ void k_cursor() {
    int i = blockIdx.x * blockDim.x + threadIdx.x;
    if (i < kNBk) g_cursor[i << 4] = (unsigned)(i * kCap);
}

// Fused: blocks [0,zb) zero out[]; blocks [zb,..) partition 4096-pt chunks
// with 512 threads (8 pts/thread).
__global__ void __launch_bounds__(512) k_main(const float* __restrict__ xyz,
                                              const int* __restrict__ bidx, int n,
                                              float* __restrict__ out, int total,
                                              int zb) {
    const int tid = threadIdx.x;
    if (blockIdx.x < zb) {
        int t = blockIdx.x * blockDim.x + tid;
        int S = zb * blockDim.x;
        float4 f4 = make_float4(0.f, 0.f, 0.f, 0.f);
        float4* o4 = (float4*)out;
        const int no4 = total >> 2;
        for (int i = t; i < no4; i += S) o4[i] = f4;
        for (int i = (no4 << 2) + t; i < total; i += S) out[i] = 0.f;
        return;
    }
    const int chunk0 = (blockIdx.x - zb) * kChunk;
    if (chunk0 >= n) return;

    __shared__ unsigned s_cnt[kNBk], s_scan[kNBk], s_gbase[kNBk];
    __shared__ unsigned s_wsum[8];
    __shared__ int s_mm[8][4];
    __shared__ unsigned long long s_key[kChunk];
    __shared__ unsigned short s_cell[kChunk];
    for (int i = tid; i < kNBk; i += kB) s_cnt[i] = 0;
    __syncthreads();

    // --- 8 points/thread, constant-indexed state (VGPR-resident) ---
    unsigned hb[8], flu[8], rank[8];
    bool val[8];
    int mnr = INT_MAX, mxr = INT_MIN, mnc = INT_MAX, mxc = INT_MIN;
    const f32x4* p = (const f32x4*)xyz;
    const i32x4* bp = (const i32x4*)bidx;
    const int g0 = (chunk0 >> 2) + tid;     // 4-pt group id, +512 per round
#pragma unroll
    for (int k = 0; k < 2; ++k) {
        const int gidx = g0 + (k << 9);
        const int pbase = gidx << 2;
        float xs[4], hs[4], zs[4]; int bs[4];
        if (pbase + 3 < n) {
            f32x4 f0 = p[3 * gidx + 0];   // x0 h0 z0 x1
            f32x4 f1 = p[3 * gidx + 1];   // h1 z1 x2 h2
            f32x4 f2 = p[3 * gidx + 2];   // z2 x3 h3 z3
            i32x4 b4 = bp[gidx];
            xs[0]=f0.x; hs[0]=f0.y; zs[0]=f0.z;
            xs[1]=f0.w; hs[1]=f1.x; zs[1]=f1.y;
            xs[2]=f1.z; hs[2]=f1.w; zs[2]=f2.x;
            xs[3]=f2.y; hs[3]=f2.z; zs[3]=f2.w;
            bs[0]=b4.x; bs[1]=b4.y; bs[2]=b4.z; bs[3]=b4.w;
        } else {
#pragma unroll
            for (int j = 0; j < 4; ++j) {
                int i = pbase + j;
                bool v = i < n;
                xs[j] = v ? xyz[3 * i + 0] : 0.f;
                hs[j] = v ? xyz[3 * i + 1] : 0.f;
                zs[j] = v ? xyz[3 * i + 2] : 0.f;
                bs[j] = v ? bidx[i] : 0;
            }
        }
#pragma unroll
        for (int j = 0; j < 4; ++j) {
            const int e = (k << 2) + j;           // constant index
            bool v = (pbase + j) < n;
            val[e] = v;
            int qr = quant(zs[j]);
            int qc = quant(xs[j]);
            if (v) {
                mnr = min(mnr, qr); mxr = max(mxr, qr);
                mnc = min(mnc, qc); mxc = max(mxc, qc);
            }
            long long fl = (long long)bs[j] * 640000 + (long long)qr * 800 + qc;
            unsigned f = (unsigned)min(max(fl, 0LL), (long long)kMaxFlat);
            flu[e] = f;
            hb[e] = __float_as_uint(hs[j]);
            rank[e] = v ? (unsigned)atomicAdd(&s_cnt[f >> 12], 1u) : 0u;
        }
    }
    // minmax block-reduce (okfast gate + fallback geometry)
#pragma unroll
    for (int off = 32; off > 0; off >>= 1) {
        mnr = min(mnr, __shfl_down(mnr, off));
        mxr = max(mxr, __shfl_down(mxr, off));
        mnc = min(mnc, __shfl_down(mnc, off));
        mxc = max(mxc, __shfl_down(mxc, off));
    }
    const int w = tid >> 6, lane = tid & 63;
    if (lane == 0) {
        s_mm[w][0] = mnr; s_mm[w][1] = mxr; s_mm[w][2] = mnc; s_mm[w][3] = mxc;
    }
    __syncthreads();   // counts final + minmax partials
    if (tid == 0) {
        int a0 = INT_MAX, a1 = INT_MIN, a2 = INT_MAX, a3 = INT_MIN;
#pragma unroll
        for (int i = 0; i < 8; ++i) {
            a0 = min(a0, s_mm[i][0]); a1 = max(a1, s_mm[i][1]);
            a2 = min(a2, s_mm[i][2]); a3 = max(a3, s_mm[i][3]);
        }
        atomicMin(&g_minr, a0); atomicMax(&g_maxr, a1);
        atomicMin(&g_minc, a2); atomicMax(&g_maxc, a3);
    }
    // parallel exclusive scan of s_cnt[0..626) -> s_scan (2 elems/thread)
    int e0 = tid * 2;
    unsigned l0 = (e0 + 0 < kNBk) ? s_cnt[e0 + 0] : 0u;
    unsigned l1 = (e0 + 1 < kNBk) ? s_cnt[e0 + 1] : 0u;
    unsigned tsum = l0 + l1;
    unsigned inc = tsum;
#pragma unroll
    for (int off = 1; off < 64; off <<= 1) {
        unsigned v = __shfl_up(inc, off);
        if (lane >= off) inc += v;
    }
    if (lane == 63) s_wsum[w] = inc;
    __syncthreads();
    if (tid == 0) {
        unsigned a = 0;
#pragma unroll
        for (int i = 0; i < 8; ++i) { unsigned t = s_wsum[i]; s_wsum[i] = a; a += t; }
    }
    __syncthreads();
    unsigned excl = inc - tsum + s_wsum[w];
    if (e0 + 0 < kNBk) s_scan[e0 + 0] = excl;
    if (e0 + 1 < kNBk) s_scan[e0 + 1] = excl + l0;
    __syncthreads();
    // cursor reservation (one padded-line atomic per nonempty bucket)
    for (int i = tid; i < kNBk; i += kB) {
        unsigned c = s_cnt[i];
        if (c) {
            unsigned pos = atomicAdd(&g_cursor[i << 4], c);
            if (pos + c > (unsigned)((i + 1) * kCap)) { g_fb = 1; s_gbase[i] = 0xFFFFFFFFu; }
            else s_gbase[i] = pos;
        }
    }
    // stage bucket-sorted into LDS
#pragma unroll
    for (int e = 0; e < 8; ++e) {
        if (val[e]) {
            const int k = e >> 2, j = e & 3;
            unsigned idx = (unsigned)(((g0 + (k << 9)) << 2) + j);
            unsigned pos = s_scan[flu[e] >> 12] + rank[e];
            s_key[pos] = ((unsigned long long)hb[e] << 32) | idx;
            s_cell[pos] = (unsigned short)(flu[e] & 4095u);
        }
    }
    __syncthreads();
    // run-walk copy-out, 8 waves (R24 pattern: consecutive lanes->consecutive dst)
    for (int r = w; r < kNBk; r += 8) {
        unsigned c = s_cnt[r];
        if (!c) continue;
        unsigned gb = s_gbase[r];
        if (gb == 0xFFFFFFFFu) continue;
        unsigned sb = s_scan[r];
        for (unsigned i = lane; i < c; i += 64) {
            g_keyb[gb + i] = s_key[sb + i];
            g_cellb[gb + i] = s_cell[sb + i];
        }
    }
}

// Per-bucket LDS reduce: max hbits per cell, then min idx among bit-equal
// maxers (== ref's two-scatter). Winners straight to out (pre-zeroed).
__global__ void __launch_bounds__(256) k_reduce(int n, float* __restrict__ out) {
    if (g_fb || !okfast()) return;
    __shared__ unsigned s_hmax[4096], s_imin[4096];
    const int tid = threadIdx.x;
    const int bk = blockIdx.x;
    for (int i = tid; i < 4096; i += 256) { s_hmax[i] = 0u; s_imin[i] = 0xFFFFFFFFu; }
    __syncthreads();
    const unsigned lo = (unsigned)(bk * kCap);
    unsigned hi = g_cursor[bk << 4];
    const unsigned cap = (unsigned)((bk + 1) * kCap);
    if (hi > cap) hi = cap;
    for (unsigned i = lo + tid; i < hi; i += 256)
        atomicMax(&s_hmax[g_cellb[i]], (unsigned)(g_keyb[i] >> 32));
    __syncthreads();
    for (unsigned i = lo + tid; i < hi; i += 256) {
        unsigned long long k = g_keyb[i];
        unsigned c = g_cellb[i];
        if ((unsigned)(k >> 32) == s_hmax[c])
            atomicMin(&s_imin[c], (unsigned)k);
    }
    __syncthreads();
    for (int c = tid; c < 4096; c += 256) {
        unsigned im = s_imin[c];
        if (im != 0xFFFFFFFFu) {
            out[im] = __uint_as_float(s_hmax[c]);   // [0,n) kept_heights
            out[n + im] = 1.0f;                     // [n,2n) keep
        }
    }
}

// ---- gated fallback chain (exact R14 logic; runs only if needed) ----
__global__ void k_fb_zero() {
    if (!g_fb && okfast()) return;
    int i = blockIdx.x * blockDim.x + threadIdx.x;
    int stride = gridDim.x * blockDim.x;
    for (int c = i; c < kNumCells; c += stride) g_cell[c] = 0ULL;
}
__global__ void k_fb_scatter(const float* __restrict__ xyz,
                             const int* __restrict__ bidx, int n) {
    if (!g_fb && okfast()) return;
    const int minr = g_minr, minc = g_minc;
    const int rmax = g_maxr - minr, cmax = g_maxc - minc;
    int t = blockIdx.x * blockDim.x + threadIdx.x;
    int S = gridDim.x * blockDim.x;
    for (int i = t; i < n; i += S) {
        float x = xyz[3 * i + 0], h = xyz[3 * i + 1], z = xyz[3 * i + 2];
        int qr = quant(z) - minr, qc = quant(x) - minc;
        int flat = bidx[i] * (rmax * cmax) + qr * cmax + qc;
        if (flat >= 0 && flat < kNumCells) {
            unsigned long long key =
                ((unsigned long long)__float_as_uint(h) << 32) | (unsigned)(~i);
            if (key > g_cell[flat]) atomicMax(&g_cell[flat], key);
        }
    }
}
__global__ void k_fb_fin(int n, float* __restrict__ out) {
    if (!g_fb && okfast()) return;
    int i = blockIdx.x * blockDim.x + threadIdx.x;
    int stride = gridDim.x * blockDim.x;
    for (int c = i; c < kNumCells; c += stride) {
        unsigned long long key = g_cell[c];
        if (key == 0ULL) continue;
        unsigned winner = ~(unsigned)key;
        out[winner] = __uint_as_float((unsigned)(key >> 32));
        out[n + winner] = 1.0f;
    }
}
__global__ void k_reset() {
    if (threadIdx.x == 0 && blockIdx.x == 0) {
        g_fb = 0;
        g_minr = INT_MAX; g_maxr = INT_MIN;
        g_minc = INT_MAX; g_maxc = INT_MIN;
    }
}

extern "C" void kernel_launch(void* const* d_in, const int* in_sizes, int n_in,
                              void* d_out, int out_size, void* d_ws, size_t ws_size,
                              hipStream_t stream) {
    const float* xyz = (const float*)d_in[0];
    const int* bidx = (const int*)d_in[1];
    // d_in[2] (semantics) unused by the reference.
    int n = in_sizes[1];

    const int zb = 256;                         // 512-thread zero blocks
    int gridMain = zb + (n + kChunk - 1) / kChunk;  // 256 + 2048
    k_cursor<<<(kNBk + 255) / 256, 256, 0, stream>>>();
    k_main<<<gridMain, kB, 0, stream>>>(xyz, bidx, n, (float*)d_out, out_size, zb);
    k_reduce<<<kNBk, 256, 0, stream>>>(n, (float*)d_out);
    k_fb_zero<<<2048, 256, 0, stream>>>();
    k_fb_scatter<<<4096, 256, 0, stream>>>(xyz, bidx, n);
    k_fb_fin<<<2048, 256, 0, stream>>>(n, (float*)d_out);
    k_reset<<<1, 64, 0, stream>>>();
}

// Round 28
// 256.007 us; speedup vs baseline: 1.3793x; 1.0454x over previous
//
#include <hip/hip_runtime.h>
#include <climits>

// R28: R27 + all-lane copy-out (R26 scheme, exonerated: its WRITE blow-up was
// the 2048 chunk, not the scheme) at 4096 chunk. s_gbase deleted: delta =
// gbase - scan folded into s_cnt after reservation; staged u32 = (bkt<<12)|cell.
// LDS 54.3KB => still 3 blocks/CU at 512 threads (24 waves).
static constexpr int kN = 8388608;
static constexpr int kNumCells = 3216822;     // fallback cell array
static constexpr int kMaxFlat = 2560800;      // 3*640000 + 800*800 + 800
static constexpr int kNBk = (kMaxFlat >> 12) + 1;   // 626 buckets x 4096 cells
static constexpr int kCap = 16384;            // per-bucket cap (mean 13.4K)
static constexpr int kChunk = 4096;           // points per part-block
static constexpr int kB = 512;                // threads per block (8 waves)

typedef float __attribute__((ext_vector_type(4))) f32x4;
typedef int   __attribute__((ext_vector_type(4))) i32x4;

__device__ __align__(16) unsigned long long g_keyb[(unsigned)kNBk * kCap]; // hbits<<32|idx
__device__ __align__(16) unsigned short g_cellb[(unsigned)kNBk * kCap];    // flat & 4095
__device__ unsigned g_cursor[kNBk * 16];      // 64B-padded cursors
__device__ unsigned long long g_cell[kNumCells];   // fallback path only
__device__ int g_minr = INT_MAX, g_maxr = INT_MIN;
__device__ int g_minc = INT_MAX, g_maxc = INT_MIN;
__device__ int g_fb = 0;

__device__ __forceinline__ int quant(float v) {
    return (int)rintf(v * 40.0f);   // np-ref rule (proven R11/R12)
}
__device__ __forceinline__ bool okfast() {
    return g_minr == 0 && g_maxr == 800 && g_minc == 0 && g_maxc == 800;
}

__global__ void k_cursor() {
    int i = blockIdx.x * blockDim.x + threadIdx.x;
    if (i < kNBk) g_cursor[i << 4] = (unsigned)(i * kCap);
}

// Fused: blocks [0,zb) zero out[]; blocks [zb,..) partition 4096-pt chunks
// with 512 threads (8 pts/thread).
__global__ void __launch_bounds__(512) k_main(const float* __restrict__ xyz,
                                              const int* __restrict__ bidx, int n,
                                              float* __restrict__ out, int total,
                                              int zb) {
    const int tid = threadIdx.x;
    if (blockIdx.x < zb) {
        int t = blockIdx.x * blockDim.x + tid;
        int S = zb * blockDim.x;
        float4 f4 = make_float4(0.f, 0.f, 0.f, 0.f);
        float4* o4 = (float4*)out;
        const int no4 = total >> 2;
        for (int i = t; i < no4; i += S) o4[i] = f4;
        for (int i = (no4 << 2) + t; i < total; i += S) out[i] = 0.f;
        return;
    }
    const int chunk0 = (blockIdx.x - zb) * kChunk;
    if (chunk0 >= n) return;

    __shared__ unsigned s_cnt[kNBk];      // counts -> (after reservation) delta
    __shared__ unsigned s_scan[kNBk];
    __shared__ unsigned s_wsum[8];
    __shared__ int s_mm[8][4];
    __shared__ unsigned long long s_key[kChunk];
    __shared__ unsigned s_cb[kChunk];     // (bkt<<12) | cell
    for (int i = tid; i < kNBk; i += kB) s_cnt[i] = 0;
    __syncthreads();

    // --- 8 points/thread, constant-indexed state (VGPR-resident) ---
    unsigned hb[8], flu[8], rank[8];
    bool val[8];
    int mnr = INT_MAX, mxr = INT_MIN, mnc = INT_MAX, mxc = INT_MIN;
    const f32x4* p = (const f32x4*)xyz;
    const i32x4* bp = (const i32x4*)bidx;
    const int g0 = (chunk0 >> 2) + tid;     // 4-pt group id, +512 per round
#pragma unroll
    for (int k = 0; k < 2; ++k) {
        const int gidx = g0 + (k << 9);
        const int pbase = gidx << 2;
        float xs[4], hs[4], zs[4]; int bs[4];
        if (pbase + 3 < n) {
            f32x4 f0 = p[3 * gidx + 0];   // x0 h0 z0 x1
            f32x4 f1 = p[3 * gidx + 1];   // h1 z1 x2 h2
            f32x4 f2 = p[3 * gidx + 2];   // z2 x3 h3 z3
            i32x4 b4 = bp[gidx];
            xs[0]=f0.x; hs[0]=f0.y; zs[0]=f0.z;
            xs[1]=f0.w; hs[1]=f1.x; zs[1]=f1.y;
            xs[2]=f1.z; hs[2]=f1.w; zs[2]=f2.x;
            xs[3]=f2.y; hs[3]=f2.z; zs[3]=f2.w;
            bs[0]=b4.x; bs[1]=b4.y; bs[2]=b4.z; bs[3]=b4.w;
        } else {
#pragma unroll
            for (int j = 0; j < 4; ++j) {
                int i = pbase + j;
                bool v = i < n;
                xs[j] = v ? xyz[3 * i + 0] : 0.f;
                hs[j] = v ? xyz[3 * i + 1] : 0.f;
                zs[j] = v ? xyz[3 * i + 2] : 0.f;
                bs[j] = v ? bidx[i] : 0;
            }
        }
#pragma unroll
        for (int j = 0; j < 4; ++j) {
            const int e = (k << 2) + j;           // constant index
            bool v = (pbase + j) < n;
            val[e] = v;
            int qr = quant(zs[j]);
            int qc = quant(xs[j]);
            if (v) {
                mnr = min(mnr, qr); mxr = max(mxr, qr);
                mnc = min(mnc, qc); mxc = max(mxc, qc);
            }
            long long fl = (long long)bs[j] * 640000 + (long long)qr * 800 + qc;
            unsigned f = (unsigned)min(max(fl, 0LL), (long long)kMaxFlat);
            flu[e] = f;
            hb[e] = __float_as_uint(hs[j]);
            rank[e] = v ? (unsigned)atomicAdd(&s_cnt[f >> 12], 1u) : 0u;
        }
    }
    // minmax block-reduce (okfast gate + fallback geometry)
#pragma unroll
    for (int off = 32; off > 0; off >>= 1) {
        mnr = min(mnr, __shfl_down(mnr, off));
        mxr = max(mxr, __shfl_down(mxr, off));
        mnc = min(mnc, __shfl_down(mnc, off));
        mxc = max(mxc, __shfl_down(mxc, off));
    }
    const int w = tid >> 6, lane = tid & 63;
    if (lane == 0) {
        s_mm[w][0] = mnr; s_mm[w][1] = mxr; s_mm[w][2] = mnc; s_mm[w][3] = mxc;
    }
    __syncthreads();   // counts final + minmax partials
    if (tid == 0) {
        int a0 = INT_MAX, a1 = INT_MIN, a2 = INT_MAX, a3 = INT_MIN;
#pragma unroll
        for (int i = 0; i < 8; ++i) {
            a0 = min(a0, s_mm[i][0]); a1 = max(a1, s_mm[i][1]);
            a2 = min(a2, s_mm[i][2]); a3 = max(a3, s_mm[i][3]);
        }
        atomicMin(&g_minr, a0); atomicMax(&g_maxr, a1);
        atomicMin(&g_minc, a2); atomicMax(&g_maxc, a3);
    }
    // parallel exclusive scan of s_cnt[0..626) -> s_scan (2 elems/thread)
    int e0 = tid * 2;
    unsigned l0 = (e0 + 0 < kNBk) ? s_cnt[e0 + 0] : 0u;
    unsigned l1 = (e0 + 1 < kNBk) ? s_cnt[e0 + 1] : 0u;
    unsigned tsum = l0 + l1;
    unsigned inc = tsum;
#pragma unroll
    for (int off = 1; off < 64; off <<= 1) {
        unsigned v = __shfl_up(inc, off);
        if (lane >= off) inc += v;
    }
    if (lane == 63) s_wsum[w] = inc;
    __syncthreads();
    if (tid == 0) {
        unsigned a = 0;
#pragma unroll
        for (int i = 0; i < 8; ++i) { unsigned t = s_wsum[i]; s_wsum[i] = a; a += t; }
    }
    __syncthreads();
    unsigned excl = inc - tsum + s_wsum[w];
    if (e0 + 0 < kNBk) s_scan[e0 + 0] = excl;
    if (e0 + 1 < kNBk) s_scan[e0 + 1] = excl + l0;
    __syncthreads();
    // cursor reservation; fold delta = gbase - scan into s_cnt.
    // Overflow (practically impossible, 26 sigma): delta=0 -> dst=i in [0,4096)
    // stays in-bounds (bucket 0 region); g_fb fallback owns correctness.
    for (int i = tid; i < kNBk; i += kB) {
        unsigned c = s_cnt[i];
        if (c) {
            unsigned pos = atomicAdd(&g_cursor[i << 4], c);
            if (pos + c > (unsigned)((i + 1) * kCap)) { g_fb = 1; s_cnt[i] = 0u; }
            else s_cnt[i] = pos - s_scan[i];
        }
    }
    // stage bucket-sorted into LDS (runs concurrently with reservation)
#pragma unroll
    for (int e = 0; e < 8; ++e) {
        if (val[e]) {
            const int k = e >> 2, j = e & 3;
            unsigned idx = (unsigned)(((g0 + (k << 9)) << 2) + j);
            unsigned pos = s_scan[flu[e] >> 12] + rank[e];
            s_key[pos] = ((unsigned long long)hb[e] << 32) | idx;
            s_cb[pos] = ((flu[e] >> 12) << 12) | (flu[e] & 4095u);  // == flu[e]
        }
    }
    __syncthreads();
    // all-lane copy-out: dst = delta[bkt] + i; consecutive i -> piecewise-
    // consecutive dst (runs ~6.5 at 4096 chunk => same DRAM pattern as R24/27).
    const int nstaged = min(n - chunk0, kChunk);
    for (int i = tid; i < nstaged; i += kB) {
        unsigned cb = s_cb[i];
        unsigned bkt = cb >> 12;
        unsigned dst = s_cnt[bkt] + (unsigned)i;   // s_cnt holds delta
        g_keyb[dst] = s_key[i];
        g_cellb[dst] = (unsigned short)(cb & 4095u);
    }
}

// Per-bucket LDS reduce: max hbits per cell, then min idx among bit-equal
// maxers (== ref's two-scatter). Winners straight to out (pre-zeroed).
__global__ void __launch_bounds__(256) k_reduce(int n, float* __restrict__ out) {
    if (g_fb || !okfast()) return;
    __shared__ unsigned s_hmax[4096], s_imin[4096];
    const int tid = threadIdx.x;
    const int bk = blockIdx.x;
    for (int i = tid; i < 4096; i += 256) { s_hmax[i] = 0u; s_imin[i] = 0xFFFFFFFFu; }
    __syncthreads();
    const unsigned lo = (unsigned)(bk * kCap);
    unsigned hi = g_cursor[bk << 4];
    const unsigned cap = (unsigned)((bk + 1) * kCap);
    if (hi > cap) hi = cap;
    for (unsigned i = lo + tid; i < hi; i += 256)
        atomicMax(&s_hmax[g_cellb[i]], (unsigned)(g_keyb[i] >> 32));
    __syncthreads();
    for (unsigned i = lo + tid; i < hi; i += 256) {
        unsigned long long k = g_keyb[i];
        unsigned c = g_cellb[i];
        if ((unsigned)(k >> 32) == s_hmax[c])
            atomicMin(&s_imin[c], (unsigned)k);
    }
    __syncthreads();
    for (int c = tid; c < 4096; c += 256) {
        unsigned im = s_imin[c];
        if (im != 0xFFFFFFFFu) {
            out[im] = __uint_as_float(s_hmax[c]);   // [0,n) kept_heights
            out[n + im] = 1.0f;                     // [n,2n) keep
        }
    }
}

// ---- gated fallback chain (exact R14 logic; runs only if needed) ----
__global__ void k_fb_zero() {
    if (!g_fb && okfast()) return;
    int i = blockIdx.x * blockDim.x + threadIdx.x;
    int stride = gridDim.x * blockDim.x;
    for (int c = i; c < kNumCells; c += stride) g_cell[c] = 0ULL;
}
__global__ void k_fb_scatter(const float* __restrict__ xyz,
                             const int* __restrict__ bidx, int n) {
    if (!g_fb && okfast()) return;
    const int minr = g_minr, minc = g_minc;
    const int rmax = g_maxr - minr, cmax = g_maxc - minc;
    int t = blockIdx.x * blockDim.x + threadIdx.x;
    int S = gridDim.x * blockDim.x;
    for (int i = t; i < n; i += S) {
        float x = xyz[3 * i + 0], h = xyz[3 * i + 1], z = xyz[3 * i + 2];
        int qr = quant(z) - minr, qc = quant(x) - minc;
        int flat = bidx[i] * (rmax * cmax) + qr * cmax + qc;
        if (flat >= 0 && flat < kNumCells) {
            unsigned long long key =
                ((unsigned long long)__float_as_uint(h) << 32) | (unsigned)(~i);
            if (key > g_cell[flat]) atomicMax(&g_cell[flat], key);
        }
    }
}
__global__ void k_fb_fin(int n, float* __restrict__ out) {
    if (!g_fb && okfast()) return;
    int i = blockIdx.x * blockDim.x + threadIdx.x;
    int stride = gridDim.x * blockDim.x;
    for (int c = i; c < kNumCells; c += stride) {
        unsigned long long key = g_cell[c];
        if (key == 0ULL) continue;
        unsigned winner = ~(unsigned)key;
        out[winner] = __uint_as_float((unsigned)(key >> 32));
        out[n + winner] = 1.0f;
    }
}
__global__ void k_reset() {
    if (threadIdx.x == 0 && blockIdx.x == 0) {
        g_fb = 0;
        g_minr = INT_MAX; g_maxr = INT_MIN;
        g_minc = INT_MAX; g_maxc = INT_MIN;
    }
}

extern "C" void kernel_launch(void* const* d_in, const int* in_sizes, int n_in,
                              void* d_out, int out_size, void* d_ws, size_t ws_size,
                              hipStream_t stream) {
    const float* xyz = (const float*)d_in[0];
    const int* bidx = (const int*)d_in[1];
    // d_in[2] (semantics) unused by the reference.
    int n = in_sizes[1];

    const int zb = 256;                         // 512-thread zero blocks
    int gridMain = zb + (n + kChunk - 1) / kChunk;  // 256 + 2048
    k_cursor<<<(kNBk + 255) / 256, 256, 0, stream>>>();
    k_main<<<gridMain, kB, 0, stream>>>(xyz, bidx, n, (float*)d_out, out_size, zb);
    k_reduce<<<kNBk, 256, 0, stream>>>(n, (float*)d_out);
    k_fb_zero<<<2048, 256, 0, stream>>>();
    k_fb_scatter<<<4096, 256, 0, stream>>>(xyz, bidx, n);
    k_fb_fin<<<2048, 256, 0, stream>>>(n, (float*)d_out);
    k_reset<<<1, 64, 0, stream>>>();
}

// Round 29
// 242.503 us; speedup vs baseline: 1.4561x; 1.0557x over previous
//
#include <hip/hip_runtime.h>
#include <climits>

// R29: R28 exactly, minus 171 bytes of LDS. R28's 54784B block was just over
// the 3-blocks/CU boundary (160KiB/3 = 54613B) -> 2 blocks/CU, occ 38%.
// Fix: alias s_mm (128B) + s_wsum (32B) into s_key's storage (phase-disjoint:
// used between syncs 2-4; s_key written only after sync 4). 54160B -> 3 blocks.
static constexpr int kN = 8388608;
static constexpr int kNumCells = 3216822;     // fallback cell array
static constexpr int kMaxFlat = 2560800;      // 3*640000 + 800*800 + 800
static constexpr int kNBk = (kMaxFlat >> 12) + 1;   // 626 buckets x 4096 cells
static constexpr int kCap = 16384;            // per-bucket cap (mean 13.4K)
static constexpr int kChunk = 4096;           // points per part-block
static constexpr int kB = 512;                // threads per block (8 waves)

typedef float __attribute__((ext_vector_type(4))) f32x4;
typedef int   __attribute__((ext_vector_type(4))) i32x4;

__device__ __align__(16) unsigned long long g_keyb[(unsigned)kNBk * kCap]; // hbits<<32|idx
__device__ __align__(16) unsigned short g_cellb[(unsigned)kNBk * kCap];    // flat & 4095
__device__ unsigned g_cursor[kNBk * 16];      // 64B-padded cursors
__device__ unsigned long long g_cell[kNumCells];   // fallback path only
__device__ int g_minr = INT_MAX, g_maxr = INT_MIN;
__device__ int g_minc = INT_MAX, g_maxc = INT_MIN;
__device__ int g_fb = 0;

__device__ __forceinline__ int quant(float v) {
    return (int)rintf(v * 40.0f);   // np-ref rule (proven R11/R12)
}
__device__ __forceinline__ bool okfast() {
    return g_minr == 0 && g_maxr == 800 && g_minc == 0 && g_maxc == 800;
}

__global__ void k_cursor() {
    int i = blockIdx.x * blockDim.x + threadIdx.x;
    if (i < kNBk) g_cursor[i << 4] = (unsigned)(i * kCap);
}

// Fused: blocks [0,zb) zero out[]; blocks [zb,..) partition 4096-pt chunks
// with 512 threads (8 pts/thread).
__global__ void __launch_bounds__(512) k_main(const float* __restrict__ xyz,
                                              const int* __restrict__ bidx, int n,
                                              float* __restrict__ out, int total,
                                              int zb) {
    const int tid = threadIdx.x;
    if (blockIdx.x < zb) {
        int t = blockIdx.x * blockDim.x + tid;
        int S = zb * blockDim.x;
        float4 f4 = make_float4(0.f, 0.f, 0.f, 0.f);
        float4* o4 = (float4*)out;
        const int no4 = total >> 2;
        for (int i = t; i < no4; i += S) o4[i] = f4;
        for (int i = (no4 << 2) + t; i < total; i += S) out[i] = 0.f;
        return;
    }
    const int chunk0 = (blockIdx.x - zb) * kChunk;
    if (chunk0 >= n) return;

    __shared__ unsigned s_cnt[kNBk];      // counts -> (after reservation) delta
    __shared__ unsigned s_scan[kNBk];
    __shared__ unsigned long long s_key[kChunk];
    __shared__ unsigned s_cb[kChunk];     // (bkt<<12) | cell
    // Phase-disjoint aliases into s_key (used only between syncs 2-4; s_key
    // is written only after sync 4):
    int* s_mm = (int*)s_key;              // [8][4] = 128 B
    unsigned* s_wsum = ((unsigned*)s_key) + 32;   // 8 x 4 B at offset 128
    for (int i = tid; i < kNBk; i += kB) s_cnt[i] = 0;
    __syncthreads();

    // --- 8 points/thread, constant-indexed state (VGPR-resident) ---
    unsigned hb[8], flu[8], rank[8];
    bool val[8];
    int mnr = INT_MAX, mxr = INT_MIN, mnc = INT_MAX, mxc = INT_MIN;
    const f32x4* p = (const f32x4*)xyz;
    const i32x4* bp = (const i32x4*)bidx;
    const int g0 = (chunk0 >> 2) + tid;     // 4-pt group id, +512 per round
#pragma unroll
    for (int k = 0; k < 2; ++k) {
        const int gidx = g0 + (k << 9);
        const int pbase = gidx << 2;
        float xs[4], hs[4], zs[4]; int bs[4];
        if (pbase + 3 < n) {
            f32x4 f0 = p[3 * gidx + 0];   // x0 h0 z0 x1
            f32x4 f1 = p[3 * gidx + 1];   // h1 z1 x2 h2
            f32x4 f2 = p[3 * gidx + 2];   // z2 x3 h3 z3
            i32x4 b4 = bp[gidx];
            xs[0]=f0.x; hs[0]=f0.y; zs[0]=f0.z;
            xs[1]=f0.w; hs[1]=f1.x; zs[1]=f1.y;
            xs[2]=f1.z; hs[2]=f1.w; zs[2]=f2.x;
            xs[3]=f2.y; hs[3]=f2.z; zs[3]=f2.w;
            bs[0]=b4.x; bs[1]=b4.y; bs[2]=b4.z; bs[3]=b4.w;
        } else {
#pragma unroll
            for (int j = 0; j < 4; ++j) {
                int i = pbase + j;
                bool v = i < n;
                xs[j] = v ? xyz[3 * i + 0] : 0.f;
                hs[j] = v ? xyz[3 * i + 1] : 0.f;
                zs[j] = v ? xyz[3 * i + 2] : 0.f;
                bs[j] = v ? bidx[i] : 0;
            }
        }
#pragma unroll
        for (int j = 0; j < 4; ++j) {
            const int e = (k << 2) + j;           // constant index
            bool v = (pbase + j) < n;
            val[e] = v;
            int qr = quant(zs[j]);
            int qc = quant(xs[j]);
            if (v) {
                mnr = min(mnr, qr); mxr = max(mxr, qr);
                mnc = min(mnc, qc); mxc = max(mxc, qc);
            }
            long long fl = (long long)bs[j] * 640000 + (long long)qr * 800 + qc;
            unsigned f = (unsigned)min(max(fl, 0LL), (long long)kMaxFlat);
            flu[e] = f;
            hb[e] = __float_as_uint(hs[j]);
            rank[e] = v ? (unsigned)atomicAdd(&s_cnt[f >> 12], 1u) : 0u;
        }
    }
    // minmax block-reduce (okfast gate + fallback geometry)
#pragma unroll
    for (int off = 32; off > 0; off >>= 1) {
        mnr = min(mnr, __shfl_down(mnr, off));
        mxr = max(mxr, __shfl_down(mxr, off));
        mnc = min(mnc, __shfl_down(mnc, off));
        mxc = max(mxc, __shfl_down(mxc, off));
    }
    const int w = tid >> 6, lane = tid & 63;
    if (lane == 0) {
        s_mm[w * 4 + 0] = mnr; s_mm[w * 4 + 1] = mxr;
        s_mm[w * 4 + 2] = mnc; s_mm[w * 4 + 3] = mxc;
    }
    __syncthreads();   // counts final + minmax partials
    if (tid == 0) {
        int a0 = INT_MAX, a1 = INT_MIN, a2 = INT_MAX, a3 = INT_MIN;
#pragma unroll
        for (int i = 0; i < 8; ++i) {
            a0 = min(a0, s_mm[i * 4 + 0]); a1 = max(a1, s_mm[i * 4 + 1]);
            a2 = min(a2, s_mm[i * 4 + 2]); a3 = max(a3, s_mm[i * 4 + 3]);
        }
        atomicMin(&g_minr, a0); atomicMax(&g_maxr, a1);
        atomicMin(&g_minc, a2); atomicMax(&g_maxc, a3);
    }
    // parallel exclusive scan of s_cnt[0..626) -> s_scan (2 elems/thread)
    int e0 = tid * 2;
    unsigned l0 = (e0 + 0 < kNBk) ? s_cnt[e0 + 0] : 0u;
    unsigned l1 = (e0 + 1 < kNBk) ? s_cnt[e0 + 1] : 0u;
    unsigned tsum = l0 + l1;
    unsigned inc = tsum;
#pragma unroll
    for (int off = 1; off < 64; off <<= 1) {
        unsigned v = __shfl_up(inc, off);
        if (lane >= off) inc += v;
    }
    if (lane == 63) s_wsum[w] = inc;
    __syncthreads();
    if (tid == 0) {
        unsigned a = 0;
#pragma unroll
        for (int i = 0; i < 8; ++i) { unsigned t = s_wsum[i]; s_wsum[i] = a; a += t; }
    }
    __syncthreads();
    unsigned excl = inc - tsum + s_wsum[w];
    if (e0 + 0 < kNBk) s_scan[e0 + 0] = excl;
    if (e0 + 1 < kNBk) s_scan[e0 + 1] = excl + l0;
    __syncthreads();   // scan done; s_mm/s_wsum dead from here (s_key reuse OK)
    // cursor reservation; fold delta = gbase - scan into s_cnt.
    // Overflow (practically impossible, 26 sigma): delta=0 -> dst=i in [0,4096)
    // stays in-bounds (bucket 0 region); g_fb fallback owns correctness.
    for (int i = tid; i < kNBk; i += kB) {
        unsigned c = s_cnt[i];
        if (c) {
            unsigned pos = atomicAdd(&g_cursor[i << 4], c);
            if (pos + c > (unsigned)((i + 1) * kCap)) { g_fb = 1; s_cnt[i] = 0u; }
            else s_cnt[i] = pos - s_scan[i];
        }
    }
    // stage bucket-sorted into LDS (runs concurrently with reservation)
#pragma unroll
    for (int e = 0; e < 8; ++e) {
        if (val[e]) {
            const int k = e >> 2, j = e & 3;
            unsigned idx = (unsigned)(((g0 + (k << 9)) << 2) + j);
            unsigned pos = s_scan[flu[e] >> 12] + rank[e];
            s_key[pos] = ((unsigned long long)hb[e] << 32) | idx;
            s_cb[pos] = flu[e];               // (bkt<<12)|cell
        }
    }
    __syncthreads();
    // all-lane copy-out: dst = delta[bkt] + i; consecutive i -> piecewise-
    // consecutive dst (runs ~6.5 at 4096 chunk => R24/27 DRAM pattern).
    const int nstaged = min(n - chunk0, kChunk);
    for (int i = tid; i < nstaged; i += kB) {
        unsigned cb = s_cb[i];
        unsigned bkt = cb >> 12;
        unsigned dst = s_cnt[bkt] + (unsigned)i;   // s_cnt holds delta
        g_keyb[dst] = s_key[i];
        g_cellb[dst] = (unsigned short)(cb & 4095u);
    }
}

// Per-bucket LDS reduce: max hbits per cell, then min idx among bit-equal
// maxers (== ref's two-scatter). Winners straight to out (pre-zeroed).
__global__ void __launch_bounds__(256) k_reduce(int n, float* __restrict__ out) {
    if (g_fb || !okfast()) return;
    __shared__ unsigned s_hmax[4096], s_imin[4096];
    const int tid = threadIdx.x;
    const int bk = blockIdx.x;
    for (int i = tid; i < 4096; i += 256) { s_hmax[i] = 0u; s_imin[i] = 0xFFFFFFFFu; }
    __syncthreads();
    const unsigned lo = (unsigned)(bk * kCap);
    unsigned hi = g_cursor[bk << 4];
    const unsigned cap = (unsigned)((bk + 1) * kCap);
    if (hi > cap) hi = cap;
    for (unsigned i = lo + tid; i < hi; i += 256)
        atomicMax(&s_hmax[g_cellb[i]], (unsigned)(g_keyb[i] >> 32));
    __syncthreads();
    for (unsigned i = lo + tid; i < hi; i += 256) {
        unsigned long long k = g_keyb[i];
        unsigned c = g_cellb[i];
        if ((unsigned)(k >> 32) == s_hmax[c])
            atomicMin(&s_imin[c], (unsigned)k);
    }
    __syncthreads();
    for (int c = tid; c < 4096; c += 256) {
        unsigned im = s_imin[c];
        if (im != 0xFFFFFFFFu) {
            out[im] = __uint_as_float(s_hmax[c]);   // [0,n) kept_heights
            out[n + im] = 1.0f;                     // [n,2n) keep
        }
    }
}

// ---- gated fallback chain (exact R14 logic; runs only if needed) ----
__global__ void k_fb_zero() {
    if (!g_fb && okfast()) return;
    int i = blockIdx.x * blockDim.x + threadIdx.x;
    int stride = gridDim.x * blockDim.x;
    for (int c = i; c < kNumCells; c += stride) g_cell[c] = 0ULL;
}
__global__ void k_fb_scatter(const float* __restrict__ xyz,
                             const int* __restrict__ bidx, int n) {
    if (!g_fb && okfast()) return;
    const int minr = g_minr, minc = g_minc;
    const int rmax = g_maxr - minr, cmax = g_maxc - minc;
    int t = blockIdx.x * blockDim.x + threadIdx.x;
    int S = gridDim.x * blockDim.x;
    for (int i = t; i < n; i += S) {
        float x = xyz[3 * i + 0], h = xyz[3 * i + 1], z = xyz[3 * i + 2];
        int qr = quant(z) - minr, qc = quant(x) - minc;
        int flat = bidx[i] * (rmax * cmax) + qr * cmax + qc;
        if (flat >= 0 && flat < kNumCells) {
            unsigned long long key =
                ((unsigned long long)__float_as_uint(h) << 32) | (unsigned)(~i);
            if (key > g_cell[flat]) atomicMax(&g_cell[flat], key);
        }
    }
}
__global__ void k_fb_fin(int n, float* __restrict__ out) {
    if (!g_fb && okfast()) return;
    int i = blockIdx.x * blockDim.x + threadIdx.x;
    int stride = gridDim.x * blockDim.x;
    for (int c = i; c < kNumCells; c += stride) {
        unsigned long long key = g_cell[c];
        if (key == 0ULL) continue;
        unsigned winner = ~(unsigned)key;
        out[winner] = __uint_as_float((unsigned)(key >> 32));
        out[n + winner] = 1.0f;
    }
}
__global__ void k_reset() {
    if (threadIdx.x == 0 && blockIdx.x == 0) {
        g_fb = 0;
        g_minr = INT_MAX; g_maxr = INT_MIN;
        g_minc = INT_MAX; g_maxc = INT_MIN;
    }
}

extern "C" void kernel_launch(void* const* d_in, const int* in_sizes, int n_in,
                              void* d_out, int out_size, void* d_ws, size_t ws_size,
                              hipStream_t stream) {
    const float* xyz = (const float*)d_in[0];
    const int* bidx = (const int*)d_in[1];
    // d_in[2] (semantics) unused by the reference.
    int n = in_sizes[1];

    const int zb = 256;                         // 512-thread zero blocks
    int gridMain = zb + (n + kChunk - 1) / kChunk;  // 256 + 2048
    k_cursor<<<(kNBk + 255) / 256, 256, 0, stream>>>();
    k_main<<<gridMain, kB, 0, stream>>>(xyz, bidx, n, (float*)d_out, out_size, zb);
    k_reduce<<<kNBk, 256, 0, stream>>>(n, (float*)d_out);
    k_fb_zero<<<2048, 256, 0, stream>>>();
    k_fb_scatter<<<4096, 256, 0, stream>>>(xyz, bidx, n);
    k_fb_fin<<<2048, 256, 0, stream>>>(n, (float*)d_out);
    k_reset<<<1, 64, 0, stream>>>();
}

// Round 30
// 236.033 us; speedup vs baseline: 1.4961x; 1.0274x over previous
//
#include <hip/hip_runtime.h>
#include <climits>

// R30: (1) single-pass k_reduce via 64-bit LDS atomicMax with key low word =
// ~idx (max-h then min-idx in one op; halves bin re-reads); (2) cursors store
// OFFSETS (static zero-init) -> k_cursor launch deleted; k_reduce resets them
// unconditionally for graph replay.
static constexpr int kN = 8388608;
static constexpr int kNumCells = 3216822;     // fallback cell array
static constexpr int kMaxFlat = 2560800;      // 3*640000 + 800*800 + 800
static constexpr int kNBk = (kMaxFlat >> 12) + 1;   // 626 buckets x 4096 cells
static constexpr int kCap = 16384;            // per-bucket cap (mean 13.4K)
static constexpr int kChunk = 4096;           // points per part-block
static constexpr int kB = 512;                // threads per block (8 waves)

typedef float __attribute__((ext_vector_type(4))) f32x4;
typedef int   __attribute__((ext_vector_type(4))) i32x4;

__device__ __align__(16) unsigned long long g_keyb[(unsigned)kNBk * kCap]; // hbits<<32|~idx
__device__ __align__(16) unsigned short g_cellb[(unsigned)kNBk * kCap];    // flat & 4095
__device__ unsigned g_cursor[kNBk * 16];      // 64B-padded OFFSET cursors (zero-init)
__device__ unsigned long long g_cell[kNumCells];   // fallback path only
__device__ int g_minr = INT_MAX, g_maxr = INT_MIN;
__device__ int g_minc = INT_MAX, g_maxc = INT_MIN;
__device__ int g_fb = 0;

__device__ __forceinline__ int quant(float v) {
    return (int)rintf(v * 40.0f);   // np-ref rule (proven R11/R12)
}
__device__ __forceinline__ bool okfast() {
    return g_minr == 0 && g_maxr == 800 && g_minc == 0 && g_maxc == 800;
}

// Fused: blocks [0,zb) zero out[]; blocks [zb,..) partition 4096-pt chunks
// with 512 threads (8 pts/thread).
__global__ void __launch_bounds__(512) k_main(const float* __restrict__ xyz,
                                              const int* __restrict__ bidx, int n,
                                              float* __restrict__ out, int total,
                                              int zb) {
    const int tid = threadIdx.x;
    if (blockIdx.x < zb) {
        int t = blockIdx.x * blockDim.x + tid;
        int S = zb * blockDim.x;
        float4 f4 = make_float4(0.f, 0.f, 0.f, 0.f);
        float4* o4 = (float4*)out;
        const int no4 = total >> 2;
        for (int i = t; i < no4; i += S) o4[i] = f4;
        for (int i = (no4 << 2) + t; i < total; i += S) out[i] = 0.f;
        return;
    }
    const int chunk0 = (blockIdx.x - zb) * kChunk;
    if (chunk0 >= n) return;

    __shared__ unsigned s_cnt[kNBk];      // counts -> (after reservation) delta
    __shared__ unsigned s_scan[kNBk];
    __shared__ unsigned long long s_key[kChunk];
    __shared__ unsigned s_cb[kChunk];     // (bkt<<12) | cell
    // Phase-disjoint aliases into s_key (used between syncs 2-4; s_key written
    // only after sync 4):
    int* s_mm = (int*)s_key;              // [8][4] = 128 B
    unsigned* s_wsum = ((unsigned*)s_key) + 32;   // 8 x 4 B at offset 128
    for (int i = tid; i < kNBk; i += kB) s_cnt[i] = 0;
    __syncthreads();

    // --- 8 points/thread, constant-indexed state (VGPR-resident) ---
    unsigned hb[8], flu[8], rank[8];
    bool val[8];
    int mnr = INT_MAX, mxr = INT_MIN, mnc = INT_MAX, mxc = INT_MIN;
    const f32x4* p = (const f32x4*)xyz;
    const i32x4* bp = (const i32x4*)bidx;
    const int g0 = (chunk0 >> 2) + tid;     // 4-pt group id, +512 per round
#pragma unroll
    for (int k = 0; k < 2; ++k) {
        const int gidx = g0 + (k << 9);
        const int pbase = gidx << 2;
        float xs[4], hs[4], zs[4]; int bs[4];
        if (pbase + 3 < n) {
            f32x4 f0 = p[3 * gidx + 0];   // x0 h0 z0 x1
            f32x4 f1 = p[3 * gidx + 1];   // h1 z1 x2 h2
            f32x4 f2 = p[3 * gidx + 2];   // z2 x3 h3 z3
            i32x4 b4 = bp[gidx];
            xs[0]=f0.x; hs[0]=f0.y; zs[0]=f0.z;
            xs[1]=f0.w; hs[1]=f1.x; zs[1]=f1.y;
            xs[2]=f1.z; hs[2]=f1.w; zs[2]=f2.x;
            xs[3]=f2.y; hs[3]=f2.z; zs[3]=f2.w;
            bs[0]=b4.x; bs[1]=b4.y; bs[2]=b4.z; bs[3]=b4.w;
        } else {
#pragma unroll
            for (int j = 0; j < 4; ++j) {
                int i = pbase + j;
                bool v = i < n;
                xs[j] = v ? xyz[3 * i + 0] : 0.f;
                hs[j] = v ? xyz[3 * i + 1] : 0.f;
                zs[j] = v ? xyz[3 * i + 2] : 0.f;
                bs[j] = v ? bidx[i] : 0;
            }
        }
#pragma unroll
        for (int j = 0; j < 4; ++j) {
            const int e = (k << 2) + j;           // constant index
            bool v = (pbase + j) < n;
            val[e] = v;
            int qr = quant(zs[j]);
            int qc = quant(xs[j]);
            if (v) {
                mnr = min(mnr, qr); mxr = max(mxr, qr);
                mnc = min(mnc, qc); mxc = max(mxc, qc);
            }
            long long fl = (long long)bs[j] * 640000 + (long long)qr * 800 + qc;
            unsigned f = (unsigned)min(max(fl, 0LL), (long long)kMaxFlat);
            flu[e] = f;
            hb[e] = __float_as_uint(hs[j]);
            rank[e] = v ? (unsigned)atomicAdd(&s_cnt[f >> 12], 1u) : 0u;
        }
    }
    // minmax block-reduce (okfast gate + fallback geometry)
#pragma unroll
    for (int off = 32; off > 0; off >>= 1) {
        mnr = min(mnr, __shfl_down(mnr, off));
        mxr = max(mxr, __shfl_down(mxr, off));
        mnc = min(mnc, __shfl_down(mnc, off));
        mxc = max(mxc, __shfl_down(mxc, off));
    }
    const int w = tid >> 6, lane = tid & 63;
    if (lane == 0) {
        s_mm[w * 4 + 0] = mnr; s_mm[w * 4 + 1] = mxr;
        s_mm[w * 4 + 2] = mnc; s_mm[w * 4 + 3] = mxc;
    }
    __syncthreads();   // counts final + minmax partials
    if (tid == 0) {
        int a0 = INT_MAX, a1 = INT_MIN, a2 = INT_MAX, a3 = INT_MIN;
#pragma unroll
        for (int i = 0; i < 8; ++i) {
            a0 = min(a0, s_mm[i * 4 + 0]); a1 = max(a1, s_mm[i * 4 + 1]);
            a2 = min(a2, s_mm[i * 4 + 2]); a3 = max(a3, s_mm[i * 4 + 3]);
        }
        atomicMin(&g_minr, a0); atomicMax(&g_maxr, a1);
        atomicMin(&g_minc, a2); atomicMax(&g_maxc, a3);
    }
    // parallel exclusive scan of s_cnt[0..626) -> s_scan (2 elems/thread)
    int e0 = tid * 2;
    unsigned l0 = (e0 + 0 < kNBk) ? s_cnt[e0 + 0] : 0u;
    unsigned l1 = (e0 + 1 < kNBk) ? s_cnt[e0 + 1] : 0u;
    unsigned tsum = l0 + l1;
    unsigned inc = tsum;
#pragma unroll
    for (int off = 1; off < 64; off <<= 1) {
        unsigned v = __shfl_up(inc, off);
        if (lane >= off) inc += v;
    }
    if (lane == 63) s_wsum[w] = inc;
    __syncthreads();
    if (tid == 0) {
        unsigned a = 0;
#pragma unroll
        for (int i = 0; i < 8; ++i) { unsigned t = s_wsum[i]; s_wsum[i] = a; a += t; }
    }
    __syncthreads();
    unsigned excl = inc - tsum + s_wsum[w];
    if (e0 + 0 < kNBk) s_scan[e0 + 0] = excl;
    if (e0 + 1 < kNBk) s_scan[e0 + 1] = excl + l0;
    __syncthreads();   // scan done; s_mm/s_wsum dead (s_key reuse OK)
    // cursor reservation (offset cursors); fold delta = bkt*kCap+pos-scan into
    // s_cnt. Overflow (26 sigma): delta=0 -> dst=i in [0,4096) (bucket 0
    // region, memory-safe); g_fb fallback owns correctness.
    for (int i = tid; i < kNBk; i += kB) {
        unsigned c = s_cnt[i];
        if (c) {
            unsigned pos = atomicAdd(&g_cursor[i << 4], c);
            if (pos + c > (unsigned)kCap) { g_fb = 1; s_cnt[i] = 0u; }
            else s_cnt[i] = (unsigned)(i * kCap) + pos - s_scan[i];
        }
    }
    // stage bucket-sorted into LDS (concurrent with reservation)
#pragma unroll
    for (int e = 0; e < 8; ++e) {
        if (val[e]) {
            const int k = e >> 2, j = e & 3;
            unsigned idx = (unsigned)(((g0 + (k << 9)) << 2) + j);
            unsigned pos = s_scan[flu[e] >> 12] + rank[e];
            s_key[pos] = ((unsigned long long)hb[e] << 32) | (unsigned)(~idx);
            s_cb[pos] = flu[e];               // (bkt<<12)|cell
        }
    }
    __syncthreads();
    // all-lane copy-out: dst = delta[bkt] + i (piecewise-consecutive runs)
    const int nstaged = min(n - chunk0, kChunk);
    for (int i = tid; i < nstaged; i += kB) {
        unsigned cb = s_cb[i];
        unsigned bkt = cb >> 12;
        unsigned dst = s_cnt[bkt] + (unsigned)i;   // s_cnt holds delta
        g_keyb[dst] = s_key[i];
        g_cellb[dst] = (unsigned short)(cb & 4095u);
    }
}

// Single-pass per-bucket reduce: 64-bit LDS atomicMax of (hbits<<32|~idx)
// == max height then min idx (exactly ref's two-scatter). Winners -> out.
// Also resets this bucket's cursor (unconditionally) for graph replay.
__global__ void __launch_bounds__(256) k_reduce(int n, float* __restrict__ out) {
    const int tid = threadIdx.x;
    const int bk = blockIdx.x;
    unsigned cnt = g_cursor[bk << 4];
    if (cnt > (unsigned)kCap) cnt = (unsigned)kCap;
    __syncthreads();
    if (tid == 0) g_cursor[bk << 4] = 0u;     // replay reset (before early-exit)
    if (g_fb || !okfast()) return;
    __shared__ unsigned long long s_cw[4096];  // 32 KB
    for (int i = tid; i < 4096; i += 256) s_cw[i] = 0ULL;
    __syncthreads();
    const unsigned lo = (unsigned)(bk * kCap);
    const unsigned hi = lo + cnt;
    for (unsigned i = lo + tid; i < hi; i += 256)
        atomicMax(&s_cw[g_cellb[i]], g_keyb[i]);
    __syncthreads();
    for (int c = tid; c < 4096; c += 256) {
        unsigned long long v = s_cw[c];
        if (v != 0ULL) {                       // real keys have low word != 0
            unsigned im = ~(unsigned)v;        // min idx among max-height pts
            out[im] = __uint_as_float((unsigned)(v >> 32));  // kept_heights
            out[n + im] = 1.0f;                               // keep
        }
    }
}

// ---- gated fallback chain (exact R14 logic; runs only if needed) ----
__global__ void k_fb_zero() {
    if (!g_fb && okfast()) return;
    int i = blockIdx.x * blockDim.x + threadIdx.x;
    int stride = gridDim.x * blockDim.x;
    for (int c = i; c < kNumCells; c += stride) g_cell[c] = 0ULL;
}
__global__ void k_fb_scatter(const float* __restrict__ xyz,
                             const int* __restrict__ bidx, int n) {
    if (!g_fb && okfast()) return;
    const int minr = g_minr, minc = g_minc;
    const int rmax = g_maxr - minr, cmax = g_maxc - minc;
    int t = blockIdx.x * blockDim.x + threadIdx.x;
    int S = gridDim.x * blockDim.x;
    for (int i = t; i < n; i += S) {
        float x = xyz[3 * i + 0], h = xyz[3 * i + 1], z = xyz[3 * i + 2];
        int qr = quant(z) - minr, qc = quant(x) - minc;
        int flat = bidx[i] * (rmax * cmax) + qr * cmax + qc;
        if (flat >= 0 && flat < kNumCells) {
            unsigned long long key =
                ((unsigned long long)__float_as_uint(h) << 32) | (unsigned)(~i);
            if (key > g_cell[flat]) atomicMax(&g_cell[flat], key);
        }
    }
}
__global__ void k_fb_fin(int n, float* __restrict__ out) {
    if (!g_fb && okfast()) return;
    int i = blockIdx.x * blockDim.x + threadIdx.x;
    int stride = gridDim.x * blockDim.x;
    for (int c = i; c < kNumCells; c += stride) {
        unsigned long long key = g_cell[c];
        if (key == 0ULL) continue;
        unsigned winner = ~(unsigned)key;
        out[winner] = __uint_as_float((unsigned)(key >> 32));
        out[n + winner] = 1.0f;
    }
}
__global__ void k_reset() {
    if (threadIdx.x == 0 && blockIdx.x == 0) {
        g_fb = 0;
        g_minr = INT_MAX; g_maxr = INT_MIN;
        g_minc = INT_MAX; g_maxc = INT_MIN;
    }
}

extern "C" void kernel_launch(void* const* d_in, const int* in_sizes, int n_in,
                              void* d_out, int out_size, void* d_ws, size_t ws_size,
                              hipStream_t stream) {
    const float* xyz = (const float*)d_in[0];
    const int* bidx = (const int*)d_in[1];
    // d_in[2] (semantics) unused by the reference.
    int n = in_sizes[1];

    const int zb = 256;                         // 512-thread zero blocks
    int gridMain = zb + (n + kChunk - 1) / kChunk;  // 256 + 2048
    k_main<<<gridMain, kB, 0, stream>>>(xyz, bidx, n, (float*)d_out, out_size, zb);
    k_reduce<<<kNBk, 256, 0, stream>>>(n, (float*)d_out);
    k_fb_zero<<<2048, 256, 0, stream>>>();
    k_fb_scatter<<<4096, 256, 0, stream>>>(xyz, bidx, n);
    k_fb_fin<<<2048, 256, 0, stream>>>(n, (float*)d_out);
    k_reset<<<1, 64, 0, stream>>>();
}

// Round 31
// 221.417 us; speedup vs baseline: 1.5948x; 1.0660x over previous
//
#include <hip/hip_runtime.h>
#include <climits>

// R31 consolidation: (1) out-zeroing folded into the 2048 partition blocks
// (uniform grid, overlaps zero-stores with input loads); (2) gated fallback
// grids shrunk 8x (cheap no-op dispatch when fast path holds); (3) k_reduce
// at 512 threads (faster bucket drain, same 32KB LDS).
static constexpr int kN = 8388608;
static constexpr int kNumCells = 3216822;     // fallback cell array
static constexpr int kMaxFlat = 2560800;      // 3*640000 + 800*800 + 800
static constexpr int kNBk = (kMaxFlat >> 12) + 1;   // 626 buckets x 4096 cells
static constexpr int kCap = 16384;            // per-bucket cap (mean 13.4K)
static constexpr int kChunk = 4096;           // points per part-block
static constexpr int kB = 512;                // threads per block (8 waves)

typedef float __attribute__((ext_vector_type(4))) f32x4;
typedef int   __attribute__((ext_vector_type(4))) i32x4;

__device__ __align__(16) unsigned long long g_keyb[(unsigned)kNBk * kCap]; // hbits<<32|~idx
__device__ __align__(16) unsigned short g_cellb[(unsigned)kNBk * kCap];    // flat & 4095
__device__ unsigned g_cursor[kNBk * 16];      // 64B-padded OFFSET cursors (zero-init)
__device__ unsigned long long g_cell[kNumCells];   // fallback path only
__device__ int g_minr = INT_MAX, g_maxr = INT_MIN;
__device__ int g_minc = INT_MAX, g_maxc = INT_MIN;
__device__ int g_fb = 0;

__device__ __forceinline__ int quant(float v) {
    return (int)rintf(v * 40.0f);   // np-ref rule (proven R11/R12)
}
__device__ __forceinline__ bool okfast() {
    return g_minr == 0 && g_maxr == 800 && g_minc == 0 && g_maxc == 800;
}

// Partition 4096-pt chunks with 512 threads (8 pts/thread). Prologue: each
// block zeroes its 1/2048 slice of out[] (fire-and-forget stores overlap the
// input loads below; kernel boundary orders them before k_reduce).
__global__ void __launch_bounds__(512) k_main(const float* __restrict__ xyz,
                                              const int* __restrict__ bidx, int n,
                                              float* __restrict__ out, int total) {
    const int tid = threadIdx.x;
    const int nblk = gridDim.x;
    {   // zero-out prologue: block b owns f32x4 groups [b*slice, (b+1)*slice)
        const int no4 = total >> 2;
        const int slice = (no4 + nblk - 1) / nblk;
        const int z0 = blockIdx.x * slice;
        const int z1 = min(z0 + slice, no4);
        float4 f4 = make_float4(0.f, 0.f, 0.f, 0.f);
        float4* o4 = (float4*)out;
        for (int i = z0 + tid; i < z1; i += kB) o4[i] = f4;
        if (blockIdx.x == 0)
            for (int i = (no4 << 2) + tid; i < total; i += kB) out[i] = 0.f;
    }
    const int chunk0 = blockIdx.x * kChunk;
    if (chunk0 >= n) return;

    __shared__ unsigned s_cnt[kNBk];      // counts -> (after reservation) delta
    __shared__ unsigned s_scan[kNBk];
    __shared__ unsigned long long s_key[kChunk];
    __shared__ unsigned s_cb[kChunk];     // (bkt<<12) | cell
    // Phase-disjoint aliases into s_key (used between syncs 2-4; s_key written
    // only after sync 4):
    int* s_mm = (int*)s_key;              // [8][4] = 128 B
    unsigned* s_wsum = ((unsigned*)s_key) + 32;   // 8 x 4 B at offset 128
    for (int i = tid; i < kNBk; i += kB) s_cnt[i] = 0;
    __syncthreads();

    // --- 8 points/thread, constant-indexed state (VGPR-resident) ---
    unsigned hb[8], flu[8], rank[8];
    bool val[8];
    int mnr = INT_MAX, mxr = INT_MIN, mnc = INT_MAX, mxc = INT_MIN;
    const f32x4* p = (const f32x4*)xyz;
    const i32x4* bp = (const i32x4*)bidx;
    const int g0 = (chunk0 >> 2) + tid;     // 4-pt group id, +512 per round
#pragma unroll
    for (int k = 0; k < 2; ++k) {
        const int gidx = g0 + (k << 9);
        const int pbase = gidx << 2;
        float xs[4], hs[4], zs[4]; int bs[4];
        if (pbase + 3 < n) {
            f32x4 f0 = p[3 * gidx + 0];   // x0 h0 z0 x1
            f32x4 f1 = p[3 * gidx + 1];   // h1 z1 x2 h2
            f32x4 f2 = p[3 * gidx + 2];   // z2 x3 h3 z3
            i32x4 b4 = bp[gidx];
            xs[0]=f0.x; hs[0]=f0.y; zs[0]=f0.z;
            xs[1]=f0.w; hs[1]=f1.x; zs[1]=f1.y;
            xs[2]=f1.z; hs[2]=f1.w; zs[2]=f2.x;
            xs[3]=f2.y; hs[3]=f2.z; zs[3]=f2.w;
            bs[0]=b4.x; bs[1]=b4.y; bs[2]=b4.z; bs[3]=b4.w;
        } else {
#pragma unroll
            for (int j = 0; j < 4; ++j) {
                int i = pbase + j;
                bool v = i < n;
                xs[j] = v ? xyz[3 * i + 0] : 0.f;
                hs[j] = v ? xyz[3 * i + 1] : 0.f;
                zs[j] = v ? xyz[3 * i + 2] : 0.f;
                bs[j] = v ? bidx[i] : 0;
            }
        }
#pragma unroll
        for (int j = 0; j < 4; ++j) {
            const int e = (k << 2) + j;           // constant index
            bool v = (pbase + j) < n;
            val[e] = v;
            int qr = quant(zs[j]);
            int qc = quant(xs[j]);
            if (v) {
                mnr = min(mnr, qr); mxr = max(mxr, qr);
                mnc = min(mnc, qc); mxc = max(mxc, qc);
            }
            long long fl = (long long)bs[j] * 640000 + (long long)qr * 800 + qc;
            unsigned f = (unsigned)min(max(fl, 0LL), (long long)kMaxFlat);
            flu[e] = f;
            hb[e] = __float_as_uint(hs[j]);
            rank[e] = v ? (unsigned)atomicAdd(&s_cnt[f >> 12], 1u) : 0u;
        }
    }
    // minmax block-reduce (okfast gate + fallback geometry)
#pragma unroll
    for (int off = 32; off > 0; off >>= 1) {
        mnr = min(mnr, __shfl_down(mnr, off));
        mxr = max(mxr, __shfl_down(mxr, off));
        mnc = min(mnc, __shfl_down(mnc, off));
        mxc = max(mxc, __shfl_down(mxc, off));
    }
    const int w = tid >> 6, lane = tid & 63;
    if (lane == 0) {
        s_mm[w * 4 + 0] = mnr; s_mm[w * 4 + 1] = mxr;
        s_mm[w * 4 + 2] = mnc; s_mm[w * 4 + 3] = mxc;
    }
    __syncthreads();   // counts final + minmax partials
    if (tid == 0) {
        int a0 = INT_MAX, a1 = INT_MIN, a2 = INT_MAX, a3 = INT_MIN;
#pragma unroll
        for (int i = 0; i < 8; ++i) {
            a0 = min(a0, s_mm[i * 4 + 0]); a1 = max(a1, s_mm[i * 4 + 1]);
            a2 = min(a2, s_mm[i * 4 + 2]); a3 = max(a3, s_mm[i * 4 + 3]);
        }
        atomicMin(&g_minr, a0); atomicMax(&g_maxr, a1);
        atomicMin(&g_minc, a2); atomicMax(&g_maxc, a3);
    }
    // parallel exclusive scan of s_cnt[0..626) -> s_scan (2 elems/thread)
    int e0 = tid * 2;
    unsigned l0 = (e0 + 0 < kNBk) ? s_cnt[e0 + 0] : 0u;
    unsigned l1 = (e0 + 1 < kNBk) ? s_cnt[e0 + 1] : 0u;
    unsigned tsum = l0 + l1;
    unsigned inc = tsum;
#pragma unroll
    for (int off = 1; off < 64; off <<= 1) {
        unsigned v = __shfl_up(inc, off);
        if (lane >= off) inc += v;
    }
    if (lane == 63) s_wsum[w] = inc;
    __syncthreads();
    if (tid == 0) {
        unsigned a = 0;
#pragma unroll
        for (int i = 0; i < 8; ++i) { unsigned t = s_wsum[i]; s_wsum[i] = a; a += t; }
    }
    __syncthreads();
    unsigned excl = inc - tsum + s_wsum[w];
    if (e0 + 0 < kNBk) s_scan[e0 + 0] = excl;
    if (e0 + 1 < kNBk) s_scan[e0 + 1] = excl + l0;
    __syncthreads();   // scan done; s_mm/s_wsum dead (s_key reuse OK)
    // cursor reservation (offset cursors); fold delta into s_cnt.
    // Overflow (26 sigma): delta=0 -> dst=i in [0,4096) (memory-safe);
    // g_fb fallback owns correctness.
    for (int i = tid; i < kNBk; i += kB) {
        unsigned c = s_cnt[i];
        if (c) {
            unsigned pos = atomicAdd(&g_cursor[i << 4], c);
            if (pos + c > (unsigned)kCap) { g_fb = 1; s_cnt[i] = 0u; }
            else s_cnt[i] = (unsigned)(i * kCap) + pos - s_scan[i];
        }
    }
    // stage bucket-sorted into LDS (concurrent with reservation)
#pragma unroll
    for (int e = 0; e < 8; ++e) {
        if (val[e]) {
            const int k = e >> 2, j = e & 3;
            unsigned idx = (unsigned)(((g0 + (k << 9)) << 2) + j);
            unsigned pos = s_scan[flu[e] >> 12] + rank[e];
            s_key[pos] = ((unsigned long long)hb[e] << 32) | (unsigned)(~idx);
            s_cb[pos] = flu[e];               // (bkt<<12)|cell
        }
    }
    __syncthreads();
    // all-lane copy-out: dst = delta[bkt] + i (piecewise-consecutive runs)
    const int nstaged = min(n - chunk0, kChunk);
    for (int i = tid; i < nstaged; i += kB) {
        unsigned cb = s_cb[i];
        unsigned bkt = cb >> 12;
        unsigned dst = s_cnt[bkt] + (unsigned)i;   // s_cnt holds delta
        g_keyb[dst] = s_key[i];
        g_cellb[dst] = (unsigned short)(cb & 4095u);
    }
}

// Single-pass per-bucket reduce (512 threads): 64-bit LDS atomicMax of
// (hbits<<32|~idx) == max height then min idx. Winners -> out. Resets this
// bucket's cursor (unconditionally) for graph replay.
__global__ void __launch_bounds__(512) k_reduce(int n, float* __restrict__ out) {
    const int tid = threadIdx.x;
    const int bk = blockIdx.x;
    unsigned cnt = g_cursor[bk << 4];
    if (cnt > (unsigned)kCap) cnt = (unsigned)kCap;
    __syncthreads();                          // all reads of cursor done
    if (tid == 0) g_cursor[bk << 4] = 0u;     // replay reset (before early-exit)
    if (g_fb || !okfast()) return;
    __shared__ unsigned long long s_cw[4096];  // 32 KB -> 3 blocks/CU @512thr
    for (int i = tid; i < 4096; i += 512) s_cw[i] = 0ULL;
    __syncthreads();
    const unsigned lo = (unsigned)(bk * kCap);
    const unsigned hi = lo + cnt;
    for (unsigned i = lo + tid; i < hi; i += 512)
        atomicMax(&s_cw[g_cellb[i]], g_keyb[i]);
    __syncthreads();
    for (int c = tid; c < 4096; c += 512) {
        unsigned long long v = s_cw[c];
        if (v != 0ULL) {                       // real keys have low word != 0
            unsigned im = ~(unsigned)v;        // min idx among max-height pts
            out[im] = __uint_as_float((unsigned)(v >> 32));  // kept_heights
            out[n + im] = 1.0f;                               // keep
        }
    }
}

// ---- gated fallback chain (exact R14 logic; small grids, grid-stride) ----
__global__ void k_fb_zero() {
    if (!g_fb && okfast()) return;
    int i = blockIdx.x * blockDim.x + threadIdx.x;
    int stride = gridDim.x * blockDim.x;
    for (int c = i; c < kNumCells; c += stride) g_cell[c] = 0ULL;
}
__global__ void k_fb_scatter(const float* __restrict__ xyz,
                             const int* __restrict__ bidx, int n) {
    if (!g_fb && okfast()) return;
    const int minr = g_minr, minc = g_minc;
    const int rmax = g_maxr - minr, cmax = g_maxc - minc;
    int t = blockIdx.x * blockDim.x + threadIdx.x;
    int S = gridDim.x * blockDim.x;
    for (int i = t; i < n; i += S) {
        float x = xyz[3 * i + 0], h = xyz[3 * i + 1], z = xyz[3 * i + 2];
        int qr = quant(z) - minr, qc = quant(x) - minc;
        int flat = bidx[i] * (rmax * cmax) + qr * cmax + qc;
        if (flat >= 0 && flat < kNumCells) {
            unsigned long long key =
                ((unsigned long long)__float_as_uint(h) << 32) | (unsigned)(~i);
            if (key > g_cell[flat]) atomicMax(&g_cell[flat], key);
        }
    }
}
__global__ void k_fb_fin(int n, float* __restrict__ out) {
    if (!g_fb && okfast()) return;
    int i = blockIdx.x * blockDim.x + threadIdx.x;
    int stride = gridDim.x * blockDim.x;
    for (int c = i; c < kNumCells; c += stride) {
        unsigned long long key = g_cell[c];
        if (key == 0ULL) continue;
        unsigned winner = ~(unsigned)key;
        out[winner] = __uint_as_float((unsigned)(key >> 32));
        out[n + winner] = 1.0f;
    }
}
__global__ void k_reset() {
    if (threadIdx.x == 0 && blockIdx.x == 0) {
        g_fb = 0;
        g_minr = INT_MAX; g_maxr = INT_MIN;
        g_minc = INT_MAX; g_maxc = INT_MIN;
    }
}

extern "C" void kernel_launch(void* const* d_in, const int* in_sizes, int n_in,
                              void* d_out, int out_size, void* d_ws, size_t ws_size,
                              hipStream_t stream) {
    const float* xyz = (const float*)d_in[0];
    const int* bidx = (const int*)d_in[1];
    // d_in[2] (semantics) unused by the reference.
    int n = in_sizes[1];

    int gridMain = (n + kChunk - 1) / kChunk;   // 2048 (uniform: zero + part)
    k_main<<<gridMain, kB, 0, stream>>>(xyz, bidx, n, (float*)d_out, out_size);
    k_reduce<<<kNBk, 512, 0, stream>>>(n, (float*)d_out);
    k_fb_zero<<<256, 256, 0, stream>>>();
    k_fb_scatter<<<512, 256, 0, stream>>>(xyz, bidx, n);
    k_fb_fin<<<256, 256, 0, stream>>>(n, (float*)d_out);
    k_reset<<<1, 64, 0, stream>>>();
}